// Round 1
// baseline (23034.991 us; speedup 1.0000x reference)
//
#include <hip/hip_runtime.h>
#include <math.h>

namespace {

constexpr int HH  = 18;
constexpr int WW  = 80;
constexpr int HW  = 1440;     // 18*80
constexpr int NB  = 8;        // batch
constexpr int CIN = 1024;

__device__ __forceinline__ float samp(const float* __restrict__ pl, int y, int x) {
  bool v = ((unsigned)y < (unsigned)HH) && ((unsigned)x < (unsigned)WW);
  float t = pl[(v ? y : 0) * WW + (v ? x : 0)];
  return v ? t : 0.f;
}

// Unified implicit-GEMM 3x3 conv / modulated-deformable conv.
//   out[o, p] = act( bn( sum_{c,k} W[o,c,k] * B(c,k,p) + bias[o] ) )
// NORMAL: B(c,k,p) = in[b, c, h+ky-1, w+kx-1] (zero pad)
// DEFORM: B(c,k,p) = bilinear(in[b,c], h-1+ky+dy, w-1+kx+dx) * sigmoid(mlogit)
// Tile: 64 out-channels x 64 pixels, BK = 8 channels * 9 taps = 72.
// 256 threads, 4x4 micro-tile per thread. LDS rows padded to 68 floats
// (stride 272B = 16*17 -> ds_read_b128 stays 16B-aligned, banks spread).
template<int DEFORM, bool NPC, bool BN, bool RELU>
__global__ __launch_bounds__(256)
void conv_gemm(const float* __restrict__ in, const float* __restrict__ wgt,
               const float* __restrict__ bias, const float* __restrict__ bng,
               const float* __restrict__ bnb, const float* __restrict__ offs,
               float* __restrict__ out, int Co)
{
  __shared__ float As[72][68];
  __shared__ float Bs[72][68];
  __shared__ float PY[9][64];
  __shared__ float PX[9][64];
  __shared__ float MM[9][64];
  __shared__ int pBs[64], pHs[64], pWs[64];

  const int tid = threadIdx.x;
  const int p0  = blockIdx.x * 64;   // pixel tile (N); 11520/64 = 180 exact
  const int o0  = blockIdx.y * 64;   // out-channel tile (M)

  if (tid < 64) {
    int p  = p0 + tid;
    int b  = p / HW;
    int hw = p - b * HW;
    int h  = hw / WW;
    int w  = hw - h * WW;
    pBs[tid] = b; pHs[tid] = h; pWs[tid] = w;
  }
  __syncthreads();

  if (DEFORM) {
    for (int q = tid; q < 9 * 64; q += 256) {
      int k = q >> 6, j = q & 63;
      int b = pBs[j], h = pHs[j], w = pWs[j];
      const float* ob = offs + ((size_t)b * 27) * HW + h * WW + w;
      float dy = ob[(size_t)k * HW];
      float dx = ob[(size_t)(9 + k) * HW];
      float ml = ob[(size_t)(18 + k) * HW];
      PY[k][j] = (float)(h - 1 + (k / 3)) + dy;
      PX[k][j] = (float)(w - 1 + (k % 3)) + dx;
      MM[k][j] = 1.f / (1.f + expf(-ml));
    }
  }
  // main loop's leading __syncthreads() makes PY/PX/MM visible before use

  // ---- loader thread mappings ----
  const int aO  = tid >> 2;          // 0..63  out-channel within tile
  const int aK0 = (tid & 3) * 18;    // 0,18,36,54  kk start (18 contiguous)
  const int bJ  = tid & 63;          // pixel within tile
  const int bR  = tid >> 6;          // 0..3    kk = bR + 4*i

  const int b_ = pBs[bJ];
  const int h_ = pHs[bJ];
  const int w_ = pWs[bJ];
  const float* bbase = in + (size_t)b_ * CIN * HW;

  // per-thread precompute (constant across all K-tiles)
  int boff[18];
  unsigned vmask = 0;
  int cA[18], kA[18];
#pragma unroll
  for (int i = 0; i < 18; ++i) {
    int kk = bR + 4 * i;
    int c  = kk / 9;
    int k  = kk - 9 * c;
    cA[i] = c; kA[i] = k;
    int y = h_ + (k / 3) - 1;
    int x = w_ + (k % 3) - 1;
    if (((unsigned)y < (unsigned)HH) && ((unsigned)x < (unsigned)WW)) vmask |= (1u << i);
    boff[i] = c * HW + y * WW + x;   // only dereferenced when valid
  }

  const int tm = tid >> 4, tn = tid & 15;
  float acc[4][4];
#pragma unroll
  for (int i = 0; i < 4; ++i)
#pragma unroll
    for (int j = 0; j < 4; ++j) acc[i][j] = 0.f;

  const int ocl = min(o0 + aO, Co - 1);            // clamp for partial M tiles
  const float* wsrc = wgt + (size_t)ocl * (CIN * 9) + aK0;

  for (int ct = 0; ct < CIN / 8; ++ct) {
    __syncthreads();
    // A tile: w[o][c0..c0+7][0..8] -> As[kk][o]
    {
      const float* s = wsrc + ct * 72;
#pragma unroll
      for (int i = 0; i < 18; ++i) As[aK0 + i][aO] = s[i];
    }
    // B tile
    {
      const float* base = bbase + (size_t)ct * 8 * HW;
      if (!DEFORM) {
#pragma unroll
        for (int i = 0; i < 18; ++i) {
          float t = ((vmask >> i) & 1u) ? base[boff[i]] : 0.f;
          Bs[bR + 4 * i][bJ] = t;
        }
      } else {
#pragma unroll
        for (int i = 0; i < 18; ++i) {
          int k   = kA[i];
          float py = PY[k][bJ];
          float px = PX[k][bJ];
          float m  = MM[k][bJ];
          float y0f = floorf(py), x0f = floorf(px);
          float wy1 = py - y0f,  wx1 = px - x0f;
          int y0 = (int)y0f, x0 = (int)x0f;
          const float* pl = base + cA[i] * HW;
          float v00 = samp(pl, y0,     x0);
          float v01 = samp(pl, y0,     x0 + 1);
          float v10 = samp(pl, y0 + 1, x0);
          float v11 = samp(pl, y0 + 1, x0 + 1);
          float vt = v00 + wx1 * (v01 - v00);
          float vb = v10 + wx1 * (v11 - v10);
          Bs[bR + 4 * i][bJ] = (vt + wy1 * (vb - vt)) * m;
        }
      }
    }
    __syncthreads();
    // compute 72 kk steps, 4x4 outer product per thread
#pragma unroll
    for (int kk = 0; kk < 72; ++kk) {
      const float4 av = *reinterpret_cast<const float4*>(&As[kk][tm * 4]);
      const float4 bv = *reinterpret_cast<const float4*>(&Bs[kk][tn * 4]);
      acc[0][0] = fmaf(av.x, bv.x, acc[0][0]);
      acc[0][1] = fmaf(av.x, bv.y, acc[0][1]);
      acc[0][2] = fmaf(av.x, bv.z, acc[0][2]);
      acc[0][3] = fmaf(av.x, bv.w, acc[0][3]);
      acc[1][0] = fmaf(av.y, bv.x, acc[1][0]);
      acc[1][1] = fmaf(av.y, bv.y, acc[1][1]);
      acc[1][2] = fmaf(av.y, bv.z, acc[1][2]);
      acc[1][3] = fmaf(av.y, bv.w, acc[1][3]);
      acc[2][0] = fmaf(av.z, bv.x, acc[2][0]);
      acc[2][1] = fmaf(av.z, bv.y, acc[2][1]);
      acc[2][2] = fmaf(av.z, bv.z, acc[2][2]);
      acc[2][3] = fmaf(av.z, bv.w, acc[2][3]);
      acc[3][0] = fmaf(av.w, bv.x, acc[3][0]);
      acc[3][1] = fmaf(av.w, bv.y, acc[3][1]);
      acc[3][2] = fmaf(av.w, bv.z, acc[3][2]);
      acc[3][3] = fmaf(av.w, bv.w, acc[3][3]);
    }
  }

  // epilogue: bias, optional BN (x*g/sqrt(1+eps)+b), optional relu, store
#pragma unroll
  for (int i = 0; i < 4; ++i) {
    int o = o0 + tm * 4 + i;
    if (o < Co) {
      float bi = bias[o];
      float sc = 1.f, sh = 0.f;
      if (BN) { sc = bng[o] * rsqrtf(1.f + 1e-5f); sh = bnb[o]; }
#pragma unroll
      for (int jj = 0; jj < 4; ++jj) {
        int j = tn * 4 + jj;
        float v = acc[i][jj] + bi;
        if (BN)   v = v * sc + sh;
        if (RELU) v = fmaxf(v, 0.f);
        if (NPC) {
          // anchor_flatten fused: out[(b*HW+hw)*Co + o]
          out[(size_t)(p0 + j) * Co + o] = v;
        } else {
          out[((size_t)pBs[j] * Co + o) * HW + pHs[j] * WW + pWs[j]] = v;
        }
      }
    }
  }
}

} // namespace

extern "C" void kernel_launch(void* const* d_in, const int* in_sizes, int n_in,
                              void* d_out, int out_size, void* d_ws, size_t ws_size,
                              hipStream_t stream) {
  const float* feat   = (const float*)d_in[0];
  const float* cls_w1 = (const float*)d_in[1];
  const float* cls_b1 = (const float*)d_in[2];
  const float* cls_w2 = (const float*)d_in[3];
  const float* cls_b2 = (const float*)d_in[4];
  const float* cls_w3 = (const float*)d_in[5];
  const float* cls_b3 = (const float*)d_in[6];
  const float* off_w  = (const float*)d_in[7];
  const float* off_b  = (const float*)d_in[8];
  const float* dcn_w  = (const float*)d_in[9];
  const float* dcn_b  = (const float*)d_in[10];
  const float* bn1_g  = (const float*)d_in[11];
  const float* bn1_b  = (const float*)d_in[12];
  const float* reg_w2 = (const float*)d_in[13];
  const float* reg_b2 = (const float*)d_in[14];
  const float* bn2_g  = (const float*)d_in[15];
  const float* bn2_b  = (const float*)d_in[16];
  const float* reg_w3 = (const float*)d_in[17];
  const float* reg_b3 = (const float*)d_in[18];

  float* outp = (float*)d_out;
  float* ws   = (float*)d_ws;
  // ws layout: bufA (47.2MB) | bufB (47.2MB) | off (1.25MB)  => ~91.2 MiB total
  const size_t ACT = (size_t)NB * 1024 * HW;   // 11,796,480 floats
  float* bufA = ws;
  float* bufB = ws + ACT;
  float* offb = ws + 2 * ACT;

  dim3 blk(256);
  const int NBLK = 11520 / 64;  // 180

  // cls branch
  conv_gemm<0, false, false, true ><<<dim3(NBLK, 16), blk, 0, stream>>>(
      feat, cls_w1, cls_b1, nullptr, nullptr, nullptr, bufA, 1024);
  conv_gemm<0, false, false, true ><<<dim3(NBLK, 16), blk, 0, stream>>>(
      bufA, cls_w2, cls_b2, nullptr, nullptr, nullptr, bufB, 1024);
  conv_gemm<0, true,  false, false><<<dim3(NBLK, 2),  blk, 0, stream>>>(
      bufB, cls_w3, cls_b3, nullptr, nullptr, nullptr, outp, 96);

  // reg branch: offset conv -> fused deformable conv (+bn1+relu) -> conv(+bn2+relu) -> head
  conv_gemm<0, false, false, false><<<dim3(NBLK, 1),  blk, 0, stream>>>(
      feat, off_w, off_b, nullptr, nullptr, nullptr, offb, 27);
  conv_gemm<1, false, true,  true ><<<dim3(NBLK, 16), blk, 0, stream>>>(
      feat, dcn_w, dcn_b, bn1_g, bn1_b, offb, bufA, 1024);
  conv_gemm<0, false, true,  true ><<<dim3(NBLK, 16), blk, 0, stream>>>(
      bufA, reg_w2, reg_b2, bn2_g, bn2_b, nullptr, bufB, 1024);
  conv_gemm<0, true,  false, false><<<dim3(NBLK, 7),  blk, 0, stream>>>(
      bufB, reg_w3, reg_b3, nullptr, nullptr, nullptr, outp + (size_t)NB * HW * 96, 416);
}

// Round 2
// 2231.618 us; speedup vs baseline: 10.3221x; 10.3221x over previous
//
#include <hip/hip_runtime.h>
#include <math.h>

typedef short short8 __attribute__((ext_vector_type(8)));
typedef float f32x4 __attribute__((ext_vector_type(4)));
typedef unsigned short u16;
typedef unsigned int u32;

#define GAS(p) ((__attribute__((address_space(1))) void*)(p))
#define LAS(p) ((__attribute__((address_space(3))) void*)(p))

namespace {

constexpr int HW   = 1440;           // 18*80
constexpr int PBAT = 20 * 82 * 1024; // padded per-batch elems

__device__ __forceinline__ u16 f2bf(float f) {
  u32 u = __float_as_uint(f);
  u32 r = (u + 0x7FFFu + ((u >> 16) & 1u)) >> 16;
  return (u16)r;
}
__device__ __forceinline__ float bf2f(u16 h) {
  return __uint_as_float(((u32)h) << 16);
}

// ---------------- NCHW fp32 -> padded NHWC bf16 ----------------
__global__ __launch_bounds__(256)
void transpose_feat(const float* __restrict__ src, u16* __restrict__ dst) {
  __shared__ float tile[128][17];
  const int bh = blockIdx.y;            // 0..143
  const int b = bh / 18, h = bh % 18;
  const int wt = blockIdx.x % 5, ct = blockIdx.x / 5;
  const int w0 = wt * 16, c0 = ct * 128;
  const int tid = threadIdx.x;
#pragma unroll
  for (int it = 0; it < 8; ++it) {
    int idx = it * 256 + tid;
    int c = idx >> 4, w = idx & 15;
    tile[c][w] = src[((size_t)(b * 1024 + c0 + c) * 18 + h) * 80 + w0 + w];
  }
  __syncthreads();
  const int px = tid >> 4, cq = tid & 15;
  union { uint4 u; u16 s[8]; } pk;
#pragma unroll
  for (int j = 0; j < 8; ++j) pk.s[j] = f2bf(tile[cq * 8 + j][px]);
  *(uint4*)(dst + ((size_t)(b * 20 + h + 1) * 82 + (w0 + px + 1)) * 1024 + c0 + cq * 8) = pk.u;
}

// ---------------- weight repack: [O][1024][3][3] f32 -> [9][O][1024] bf16 ----------------
__global__ __launch_bounds__(256)
void repack_w(const float* __restrict__ src, u16* __restrict__ dst, int O) {
  int idx = blockIdx.x * 256 + threadIdx.x;
  if (idx >= O * 128) return;
  int o = idx >> 7, c8 = idx & 127;
  const float* s = src + (size_t)o * 9216 + (size_t)c8 * 72;
  float v[72];
#pragma unroll
  for (int i = 0; i < 18; ++i) {
    float4 f = *(const float4*)(s + i * 4);
    v[i * 4 + 0] = f.x; v[i * 4 + 1] = f.y; v[i * 4 + 2] = f.z; v[i * 4 + 3] = f.w;
  }
#pragma unroll
  for (int t = 0; t < 9; ++t) {
    union { uint4 u; u16 h[8]; } pk;
#pragma unroll
    for (int j = 0; j < 8; ++j) pk.h[j] = f2bf(v[j * 9 + t]);
    *(uint4*)(dst + ((size_t)t * O + o) * 1024 + c8 * 8) = pk.u;
  }
}

// ---------------- deformable sampling: tap planes [9][Npc][1024] bf16 ----------------
__global__ __launch_bounds__(256)
void sample_k(const u16* __restrict__ featP, const float* __restrict__ offp,
              u16* __restrict__ spl, int pix0, int Npc) {
  const int tid = threadIdx.x;
  const int k = blockIdx.y;
  const int lp = blockIdx.x * 16 + (tid >> 4);
  const int p = pix0 + lp;
  const int c8 = tid & 15;
  int b = p / HW, hw = p - b * HW;
  int h = hw / 80, w = hw - h * 80;
  float dy = offp[p * 27 + k];
  float dx = offp[p * 27 + 9 + k];
  float ml = offp[p * 27 + 18 + k];
  float m = 1.f / (1.f + expf(-ml));
  float py = (float)(h - 1 + k / 3) + dy;
  float px = (float)(w - 1 + (k % 3)) + dx;
  float y0f = floorf(py), x0f = floorf(px);
  float wy1 = py - y0f, wx1 = px - x0f;
  float wy0 = 1.f - wy1, wx0 = 1.f - wx1;
  int y0 = (int)y0f, x0 = (int)x0f;
  // clamp into padded range; halo rows/cols are zero so OOB contributes 0
  int ya = min(max(y0, -1), 18),  yb = min(max(y0 + 1, -1), 18);
  int xa = min(max(x0, -1), 80),  xb = min(max(x0 + 1, -1), 80);
  const u16* base = featP + (size_t)b * PBAT;
  const u16* r00 = base + ((size_t)(ya + 1) * 82 + (xa + 1)) * 1024;
  const u16* r01 = base + ((size_t)(ya + 1) * 82 + (xb + 1)) * 1024;
  const u16* r10 = base + ((size_t)(yb + 1) * 82 + (xa + 1)) * 1024;
  const u16* r11 = base + ((size_t)(yb + 1) * 82 + (xb + 1)) * 1024;
  float w00 = wy0 * wx0 * m, w01 = wy0 * wx1 * m;
  float w10 = wy1 * wx0 * m, w11 = wy1 * wx1 * m;
  u16* dst = spl + ((size_t)k * Npc + lp) * 1024;
  for (int c = c8 * 8; c < 1024; c += 128) {
    union { uint4 u; u16 h[8]; } a, bq, cq2, d, o;
    a.u   = *(const uint4*)(r00 + c);
    bq.u  = *(const uint4*)(r01 + c);
    cq2.u = *(const uint4*)(r10 + c);
    d.u   = *(const uint4*)(r11 + c);
#pragma unroll
    for (int j = 0; j < 8; ++j) {
      float v = w00 * bf2f(a.h[j]) + w01 * bf2f(bq.h[j]) +
                w10 * bf2f(cq2.h[j]) + w11 * bf2f(d.h[j]);
      o.h[j] = f2bf(v);
    }
    *(uint4*)(dst + c) = o.u;
  }
}

// ---------------- unified MFMA implicit-GEMM conv ----------------
// A = wT [9][Co][1024] bf16. B: taps mode = padded NHWC act; planes mode = sampled planes.
// 128x128 tile, BK=32, 16x16x32 bf16 MFMA, global_load_lds(16B), XOR-swizzled LDS.
template<int PLANES, int STOREF32, int HASBN, int HASRELU>
__global__ __launch_bounds__(256)
void mfma_conv(const u16* __restrict__ W, const u16* __restrict__ Bp,
               const float* __restrict__ bias, const float* __restrict__ bng,
               const float* __restrict__ bnb, void* __restrict__ outv,
               int Co, int pix0, int Npc) {
  __shared__ __align__(16) u16 As[128 * 32];
  __shared__ __align__(16) u16 Bs[128 * 32];
  const int tid = threadIdx.x;
  const int wv = tid >> 6, lane = tid & 63;
  const int o0 = blockIdx.y * 128;
  const int p0 = pix0 + blockIdx.x * 128;

  // staging: wave wv instr s covers rows (wv*2+s)*16 .. +16; lane -> row lr=lane/4, chunk lane&3.
  // LDS position q holds data chunk q ^ ((row>>1)&3)  (row>>1 bits = (lane>>3)&3 within group)
  const int lr = lane >> 2;
  const int qs = (lane & 3) ^ ((lane >> 3) & 3);
  int aoff[2], boff[2];
#pragma unroll
  for (int s = 0; s < 2; ++s) {
    int r = (wv * 2 + s) * 16 + lr;
    int o = min(o0 + r, Co - 1);
    aoff[s] = o * 1024 + qs * 8;
    int p = p0 + r;
    if (PLANES) {
      boff[s] = (p - pix0) * 1024 + qs * 8;
    } else {
      int b = p / HW, hw = p - b * HW;
      int h = hw / 80, w = hw - h * 80;
      boff[s] = ((b * 20 + h) * 82 + w) * 1024 + qs * 8;
    }
  }
  u16* aDst = As + (wv * 2) * 512;
  u16* bDst = Bs + (wv * 2) * 512;

  const int wm = wv >> 1, wn = wv & 1;
  const int frm = lane & 15;           // m for A-frag, n for B-frag
  const int kq = lane >> 4;            // k-quad
  const int sel = (kq ^ ((lane >> 1) & 3)) * 16;  // swizzled chunk byte offset

  f32x4 acc[4][4];
#pragma unroll
  for (int i = 0; i < 4; ++i)
#pragma unroll
    for (int j = 0; j < 4; ++j) acc[i][j] = (f32x4)0.f;

  for (int t = 0; t < 9; ++t) {
    const u16* Wt = W + (size_t)t * Co * 1024;
    const u16* Bt = Bp + (PLANES ? (size_t)t * (size_t)Npc * 1024
                                 : (size_t)(((t / 3) * 82 + (t % 3)) * 1024));
    for (int cc = 0; cc < 1024; cc += 32) {
      __syncthreads();
#pragma unroll
      for (int s = 0; s < 2; ++s) {
        __builtin_amdgcn_global_load_lds(GAS(Wt + aoff[s] + cc), LAS(aDst + s * 512), 16, 0, 0);
        __builtin_amdgcn_global_load_lds(GAS(Bt + boff[s] + cc), LAS(bDst + s * 512), 16, 0, 0);
      }
      __syncthreads();
      uint4 af[4], bf4[4];
#pragma unroll
      for (int i = 0; i < 4; ++i) {
        af[i]  = *(const uint4*)((const char*)As + (wm * 64 + i * 16 + frm) * 64 + sel);
        bf4[i] = *(const uint4*)((const char*)Bs + (wn * 64 + i * 16 + frm) * 64 + sel);
      }
#pragma unroll
      for (int i = 0; i < 4; ++i) {
        short8 a = __builtin_bit_cast(short8, af[i]);
#pragma unroll
        for (int j = 0; j < 4; ++j) {
          short8 b = __builtin_bit_cast(short8, bf4[j]);
          acc[i][j] = __builtin_amdgcn_mfma_f32_16x16x32_bf16(a, b, acc[i][j], 0, 0, 0);
        }
      }
    }
  }

  // epilogue: D col(lane&15)=n(pixel), row(kq*4+r)=m(channel)
  size_t obase[4];
#pragma unroll
  for (int j = 0; j < 4; ++j) {
    int pn = p0 + wn * 64 + j * 16 + frm;
    if (STOREF32) {
      obase[j] = (size_t)pn * Co;
    } else {
      int b = pn / HW, hw = pn - b * HW;
      int h = hw / 80, w = hw - h * 80;
      obase[j] = ((size_t)(b * 20 + h + 1) * 82 + (w + 1)) * 1024;
    }
  }
#pragma unroll
  for (int i = 0; i < 4; ++i) {
    int o = o0 + wm * 64 + i * 16 + kq * 4;
    float bi[4], sc[4], sh[4];
#pragma unroll
    for (int r = 0; r < 4; ++r) {
      int oc = min(o + r, Co - 1);
      bi[r] = bias[oc];
      if (HASBN) { sc[r] = bng[oc] * rsqrtf(1.f + 1e-5f); sh[r] = bnb[oc]; }
    }
#pragma unroll
    for (int j = 0; j < 4; ++j) {
      float v[4];
#pragma unroll
      for (int r = 0; r < 4; ++r) {
        float x = acc[i][j][r] + bi[r];
        if (HASBN) x = x * sc[r] + sh[r];
        if (HASRELU) x = fmaxf(x, 0.f);
        v[r] = x;
      }
      if (STOREF32) {
        float* op = (float*)outv;
#pragma unroll
        for (int r = 0; r < 4; ++r)
          if (o + r < Co) op[obase[j] + o + r] = v[r];
      } else {
        u16* op = (u16*)outv;
        union { ulonglong1 dummy; } ;
        ushort4 pk;
        pk.x = f2bf(v[0]); pk.y = f2bf(v[1]); pk.z = f2bf(v[2]); pk.w = f2bf(v[3]);
        *(ushort4*)(op + obase[j] + o) = pk;
      }
    }
  }
}

} // namespace

extern "C" void kernel_launch(void* const* d_in, const int* in_sizes, int n_in,
                              void* d_out, int out_size, void* d_ws, size_t ws_size,
                              hipStream_t stream) {
  const float* feat   = (const float*)d_in[0];
  const float* cls_w1 = (const float*)d_in[1];
  const float* cls_b1 = (const float*)d_in[2];
  const float* cls_w2 = (const float*)d_in[3];
  const float* cls_b2 = (const float*)d_in[4];
  const float* cls_w3 = (const float*)d_in[5];
  const float* cls_b3 = (const float*)d_in[6];
  const float* off_w  = (const float*)d_in[7];
  const float* off_b  = (const float*)d_in[8];
  const float* dcn_w  = (const float*)d_in[9];
  const float* dcn_b  = (const float*)d_in[10];
  const float* bn1_g  = (const float*)d_in[11];
  const float* bn1_b  = (const float*)d_in[12];
  const float* reg_w2 = (const float*)d_in[13];
  const float* reg_b2 = (const float*)d_in[14];
  const float* bn2_g  = (const float*)d_in[15];
  const float* bn2_b  = (const float*)d_in[16];
  const float* reg_w3 = (const float*)d_in[17];
  const float* reg_b3 = (const float*)d_in[18];
  float* outp = (float*)d_out;

  // ws layout (bytes)
  const size_t ACTB = 26869760;                // 8*20*82*1024*2
  char* wsb = (char*)d_ws;
  u16* featP = (u16*)(wsb);
  u16* actA  = (u16*)(wsb + ACTB);
  u16* actB  = (u16*)(wsb + 2 * ACTB);
  u16* wts   = (u16*)(wsb + 3 * ACTB);         // 85,432,320 B
  float* offp = (float*)(wsb + 3 * ACTB + 85432320);   // 1,244,160 B
  u16* spl   = (u16*)(wsb + 3 * ACTB + 85432320 + 1244160);
  const size_t BASE = 3 * ACTB + 85432320 + 1244160;   // 167,285,760

  u16* offT = wts;
  u16* w1T  = wts + 248832;
  u16* w2T  = wts + 9686016;
  u16* w3T  = wts + 19123200;
  u16* dcnT = wts + 20007936;
  u16* r2T  = wts + 29445120;
  u16* r3T  = wts + 38882304;

  // chunking of deformable sampling to fit ws
  size_t avail = ws_size > BASE ? ws_size - BASE : 0;
  int tiles = (int)(avail / 2359296);   // bytes per 128-pixel tile of 9 planes
  if (tiles < 1) tiles = 1;
  if (tiles > 90) tiles = 90;

  dim3 blk(256);

  // zero padded activation buffers (halo must be 0; ws is poisoned each call)
  hipMemsetAsync(featP, 0, ACTB, stream);
  hipMemsetAsync(actA, 0, ACTB, stream);
  hipMemsetAsync(actB, 0, ACTB, stream);

  transpose_feat<<<dim3(40, 144), blk, 0, stream>>>(feat, featP);

  repack_w<<<dim3(14),  blk, 0, stream>>>(off_w,  offT, 27);
  repack_w<<<dim3(512), blk, 0, stream>>>(cls_w1, w1T, 1024);
  repack_w<<<dim3(512), blk, 0, stream>>>(cls_w2, w2T, 1024);
  repack_w<<<dim3(48),  blk, 0, stream>>>(cls_w3, w3T, 96);
  repack_w<<<dim3(512), blk, 0, stream>>>(dcn_w,  dcnT, 1024);
  repack_w<<<dim3(512), blk, 0, stream>>>(reg_w2, r2T, 1024);
  repack_w<<<dim3(208), blk, 0, stream>>>(reg_w3, r3T, 416);

  // offset conv (Co=27, fp32 flat [p][27])
  mfma_conv<0, 1, 0, 0><<<dim3(90, 1), blk, 0, stream>>>(
      offT, featP, off_b, nullptr, nullptr, offp, 27, 0, 0);

  // deformable conv in pixel chunks: sample -> GEMM(planes) -> actB
  for (int t0 = 0; t0 < 90; t0 += tiles) {
    int nt = (90 - t0) < tiles ? (90 - t0) : tiles;
    int pix0 = t0 * 128, np = nt * 128;
    sample_k<<<dim3(nt * 8, 9), blk, 0, stream>>>(featP, offp, spl, pix0, np);
    mfma_conv<1, 0, 1, 1><<<dim3(nt, 8), blk, 0, stream>>>(
        dcnT, spl, dcn_b, bn1_g, bn1_b, actB, 1024, pix0, np);
  }

  // cls branch
  mfma_conv<0, 0, 0, 1><<<dim3(90, 8), blk, 0, stream>>>(
      w1T, featP, cls_b1, nullptr, nullptr, actA, 1024, 0, 0);
  mfma_conv<0, 0, 0, 1><<<dim3(90, 8), blk, 0, stream>>>(
      w2T, actA, cls_b2, nullptr, nullptr, featP, 1024, 0, 0);   // reuse featP
  mfma_conv<0, 1, 0, 0><<<dim3(90, 1), blk, 0, stream>>>(
      w3T, featP, cls_b3, nullptr, nullptr, outp, 96, 0, 0);

  // reg branch tail
  mfma_conv<0, 0, 1, 1><<<dim3(90, 8), blk, 0, stream>>>(
      r2T, actB, reg_b2, bn2_g, bn2_b, actA, 1024, 0, 0);
  mfma_conv<0, 1, 0, 0><<<dim3(90, 4), blk, 0, stream>>>(
      r3T, actA, reg_b3, nullptr, nullptr, outp + 1105920, 416, 0, 0);
}